// Round 3
// baseline (176.073 us; speedup 1.0000x reference)
//
#include <hip/hip_runtime.h>

// GAE scan: T=2048, N=4096, fp32. Chunked linear-recurrence scan, 2 kernels:
//   K1: per-(chunk, env4) compose affine  adv[t0-1+L..] : adv_in -> (A, P)
//       i.e. adv at chunk bottom = P + A * adv_entering_from_above. float4 over envs.
//   K2: per-(chunk, env4): coalesced look-back over chunk summaries above
//       (b = A*b + P, c' = 63..c+1, all L2/L3-hot), then replay the chunk
//       with incoming adv = b, writing advantages and returns (float4).

#define T_LEN    2048
#define N_ENV    4096
#define NV4      (N_ENV / 4)          // 1024 float4 columns
#define N_CHUNKS 64
#define CHUNK_L  (T_LEN / N_CHUNKS)   // 32

static constexpr float GAMMA = 0.99f;
static constexpr float GL    = 0.99f * 0.95f;   // gamma * gae_lambda

__global__ __launch_bounds__(256) void gae_phase1(
    const float4* __restrict__ rewards,   // [T_LEN][NV4]
    const float4* __restrict__ values,
    const float4* __restrict__ dones,
    float4* __restrict__ Aout,            // [N_CHUNKS][NV4]
    float4* __restrict__ Pout)
{
    const int idx = blockIdx.x * blockDim.x + threadIdx.x;   // c*NV4 + n4
    const int n4 = idx & (NV4 - 1);
    const int c  = idx >> 10;
    const int t_hi = c * CHUNK_L + (CHUNK_L - 1);

    float4 v_next, d_next;
    if (c == N_CHUNKS - 1) {
        v_next = make_float4(0.f, 0.f, 0.f, 0.f);
        d_next = make_float4(1.f, 1.f, 1.f, 1.f);
    } else {
        v_next = values[(t_hi + 1) * NV4 + n4];
        d_next = dones [(t_hi + 1) * NV4 + n4];
    }

    float4 A = make_float4(1.f, 1.f, 1.f, 1.f);
    float4 P = make_float4(0.f, 0.f, 0.f, 0.f);

    #pragma unroll 8
    for (int i = 0; i < CHUNK_L; ++i) {
        const int t = t_hi - i;
        const float4 r = rewards[t * NV4 + n4];
        const float4 v = values [t * NV4 + n4];
        const float4 d = dones  [t * NV4 + n4];
        #define STEP(X) { \
            const float nt    = 1.0f - d_next.X; \
            const float delta = fmaf(GAMMA * v_next.X, nt, r.X) - v.X; \
            const float cc    = GL * nt; \
            P.X = fmaf(cc, P.X, delta); \
            A.X = cc * A.X; \
            v_next.X = v.X; d_next.X = d.X; }
        STEP(x) STEP(y) STEP(z) STEP(w)
        #undef STEP
    }
    Aout[idx] = A;
    Pout[idx] = P;
}

__global__ __launch_bounds__(256) void gae_phase23(
    const float4* __restrict__ rewards,
    const float4* __restrict__ values,
    const float4* __restrict__ dones,
    const float4* __restrict__ Ain,    // [N_CHUNKS][NV4]
    const float4* __restrict__ Pin,
    float4* __restrict__ out)          // [2*T_LEN][NV4]: advantages then returns
{
    const int idx = blockIdx.x * blockDim.x + threadIdx.x;
    const int n4 = idx & (NV4 - 1);
    const int c  = idx >> 10;
    const int t_hi = c * CHUNK_L + (CHUNK_L - 1);

    // Coalesced look-back: incoming adv for this chunk = suffix composition of
    // all chunk affines above it, applied to 0. Same order as old phase2.
    float4 adv = make_float4(0.f, 0.f, 0.f, 0.f);
    for (int c2 = N_CHUNKS - 1; c2 > c; --c2) {
        const float4 a = Ain[c2 * NV4 + n4];
        const float4 p = Pin[c2 * NV4 + n4];
        adv.x = fmaf(a.x, adv.x, p.x);
        adv.y = fmaf(a.y, adv.y, p.y);
        adv.z = fmaf(a.z, adv.z, p.z);
        adv.w = fmaf(a.w, adv.w, p.w);
    }

    float4 v_next, d_next;
    if (c == N_CHUNKS - 1) {
        v_next = make_float4(0.f, 0.f, 0.f, 0.f);
        d_next = make_float4(1.f, 1.f, 1.f, 1.f);
    } else {
        v_next = values[(t_hi + 1) * NV4 + n4];
        d_next = dones [(t_hi + 1) * NV4 + n4];
    }

    #pragma unroll 8
    for (int i = 0; i < CHUNK_L; ++i) {
        const int t = t_hi - i;
        const float4 r = rewards[t * NV4 + n4];
        const float4 v = values [t * NV4 + n4];
        const float4 d = dones  [t * NV4 + n4];
        float4 ret;
        #define STEP(X) { \
            const float nt    = 1.0f - d_next.X; \
            const float delta = fmaf(GAMMA * v_next.X, nt, r.X) - v.X; \
            const float cc    = GL * nt; \
            adv.X = fmaf(cc, adv.X, delta); \
            ret.X = adv.X + v.X; \
            v_next.X = v.X; d_next.X = d.X; }
        STEP(x) STEP(y) STEP(z) STEP(w)
        #undef STEP
        out[t * NV4 + n4]           = adv;   // advantages
        out[(T_LEN + t) * NV4 + n4] = ret;   // returns
    }
}

extern "C" void kernel_launch(void* const* d_in, const int* in_sizes, int n_in,
                              void* d_out, int out_size, void* d_ws, size_t ws_size,
                              hipStream_t stream) {
    const float4* rewards = (const float4*)d_in[0];
    const float4* values  = (const float4*)d_in[1];
    const float4* dones   = (const float4*)d_in[2];
    float4* out = (float4*)d_out;

    // Workspace: A | P, each N_CHUNKS*N_ENV fp32 (1 MB each); fully written by
    // K1 before K2 reads them (0xAA poison safe).
    float4* A = (float4*)d_ws;
    float4* P = A + (size_t)N_CHUNKS * NV4;

    const int blk = 256;
    gae_phase1<<<(N_CHUNKS * NV4) / blk, blk, 0, stream>>>(
        rewards, values, dones, A, P);
    gae_phase23<<<(N_CHUNKS * NV4) / blk, blk, 0, stream>>>(
        rewards, values, dones, A, P, out);
}

// Round 4
// 164.676 us; speedup vs baseline: 1.0692x; 1.0692x over previous
//
#include <hip/hip_runtime.h>

// GAE scan: T=2048, N=4096, fp32. Chunked linear-recurrence scan, 2 kernels:
//   K1: per-(chunk, env4) compose affine: adv_at_chunk_top = P + A*adv_from_above
//   K2: per-(chunk, env4): coalesced L2-hot look-back over chunk summaries above
//       (b = A*b + P), then replay the chunk writing advantages and returns.
// N_CHUNKS=128 (CHUNK_L=16): 131072 threads/kernel = 2048 waves = 8 waves/CU.
// (64 chunks gave only 4 waves/CU -> latency-bound at 2.9 TB/s, occ 6%.)

#define T_LEN    2048
#define N_ENV    4096
#define NV4      (N_ENV / 4)          // 1024 float4 columns
#define N_CHUNKS 128
#define CHUNK_L  (T_LEN / N_CHUNKS)   // 16

static constexpr float GAMMA = 0.99f;
static constexpr float GL    = 0.99f * 0.95f;   // gamma * gae_lambda

__global__ __launch_bounds__(256) void gae_phase1(
    const float4* __restrict__ rewards,   // [T_LEN][NV4]
    const float4* __restrict__ values,
    const float4* __restrict__ dones,
    float4* __restrict__ Aout,            // [N_CHUNKS][NV4]
    float4* __restrict__ Pout)
{
    const int idx = blockIdx.x * blockDim.x + threadIdx.x;   // c*NV4 + n4
    const int n4 = idx & (NV4 - 1);
    const int c  = idx >> 10;
    const int t_hi = c * CHUNK_L + (CHUNK_L - 1);

    float4 v_next, d_next;
    if (c == N_CHUNKS - 1) {
        v_next = make_float4(0.f, 0.f, 0.f, 0.f);
        d_next = make_float4(1.f, 1.f, 1.f, 1.f);
    } else {
        v_next = values[(t_hi + 1) * NV4 + n4];
        d_next = dones [(t_hi + 1) * NV4 + n4];
    }

    float4 A = make_float4(1.f, 1.f, 1.f, 1.f);
    float4 P = make_float4(0.f, 0.f, 0.f, 0.f);

    #pragma unroll
    for (int i = 0; i < CHUNK_L; ++i) {
        const int t = t_hi - i;
        const float4 r = rewards[t * NV4 + n4];
        const float4 v = values [t * NV4 + n4];
        const float4 d = dones  [t * NV4 + n4];
        #define STEP(X) { \
            const float nt    = 1.0f - d_next.X; \
            const float delta = fmaf(GAMMA * v_next.X, nt, r.X) - v.X; \
            const float cc    = GL * nt; \
            P.X = fmaf(cc, P.X, delta); \
            A.X = cc * A.X; \
            v_next.X = v.X; d_next.X = d.X; }
        STEP(x) STEP(y) STEP(z) STEP(w)
        #undef STEP
    }
    Aout[idx] = A;
    Pout[idx] = P;
}

__global__ __launch_bounds__(256) void gae_phase23(
    const float4* __restrict__ rewards,
    const float4* __restrict__ values,
    const float4* __restrict__ dones,
    const float4* __restrict__ Ain,    // [N_CHUNKS][NV4]
    const float4* __restrict__ Pin,
    float4* __restrict__ out)          // [2*T_LEN][NV4]: advantages then returns
{
    const int idx = blockIdx.x * blockDim.x + threadIdx.x;
    const int n4 = idx & (NV4 - 1);
    const int c  = idx >> 10;
    const int t_hi = c * CHUNK_L + (CHUNK_L - 1);

    // Coalesced look-back: incoming adv = suffix composition of chunk affines
    // above this chunk, applied to 0. A/P are 2 MB each -> L2-resident.
    float4 adv = make_float4(0.f, 0.f, 0.f, 0.f);
    #pragma unroll 4
    for (int c2 = N_CHUNKS - 1; c2 > c; --c2) {
        const float4 a = Ain[c2 * NV4 + n4];
        const float4 p = Pin[c2 * NV4 + n4];
        adv.x = fmaf(a.x, adv.x, p.x);
        adv.y = fmaf(a.y, adv.y, p.y);
        adv.z = fmaf(a.z, adv.z, p.z);
        adv.w = fmaf(a.w, adv.w, p.w);
    }

    float4 v_next, d_next;
    if (c == N_CHUNKS - 1) {
        v_next = make_float4(0.f, 0.f, 0.f, 0.f);
        d_next = make_float4(1.f, 1.f, 1.f, 1.f);
    } else {
        v_next = values[(t_hi + 1) * NV4 + n4];
        d_next = dones [(t_hi + 1) * NV4 + n4];
    }

    #pragma unroll
    for (int i = 0; i < CHUNK_L; ++i) {
        const int t = t_hi - i;
        const float4 r = rewards[t * NV4 + n4];
        const float4 v = values [t * NV4 + n4];
        const float4 d = dones  [t * NV4 + n4];
        float4 ret;
        #define STEP(X) { \
            const float nt    = 1.0f - d_next.X; \
            const float delta = fmaf(GAMMA * v_next.X, nt, r.X) - v.X; \
            const float cc    = GL * nt; \
            adv.X = fmaf(cc, adv.X, delta); \
            ret.X = adv.X + v.X; \
            v_next.X = v.X; d_next.X = d.X; }
        STEP(x) STEP(y) STEP(z) STEP(w)
        #undef STEP
        out[t * NV4 + n4]           = adv;   // advantages
        out[(T_LEN + t) * NV4 + n4] = ret;   // returns
    }
}

extern "C" void kernel_launch(void* const* d_in, const int* in_sizes, int n_in,
                              void* d_out, int out_size, void* d_ws, size_t ws_size,
                              hipStream_t stream) {
    const float4* rewards = (const float4*)d_in[0];
    const float4* values  = (const float4*)d_in[1];
    const float4* dones   = (const float4*)d_in[2];
    float4* out = (float4*)d_out;

    // Workspace: A | P, each N_CHUNKS*N_ENV fp32 (2 MB each); fully written by
    // K1 before K2 reads them (0xAA poison safe).
    float4* A = (float4*)d_ws;
    float4* P = A + (size_t)N_CHUNKS * NV4;

    const int blk = 256;
    gae_phase1<<<(N_CHUNKS * NV4) / blk, blk, 0, stream>>>(
        rewards, values, dones, A, P);
    gae_phase23<<<(N_CHUNKS * NV4) / blk, blk, 0, stream>>>(
        rewards, values, dones, A, P, out);
}